// Round 2
// baseline (26724.530 us; speedup 1.0000x reference)
//
#include <hip/hip_runtime.h>

// GRU B=32, T=2048, I=H=512.
// Phase 1 (if ws fits): ih_gemm precomputes x_gates[t][g][1536] with 2048 wgs.
// Phase 2: persistent 32-wg recurrence. wg g owns h-cols [g*16,g*16+16).
// h exchanged via tagged words in a ring: u32 = (tag<<16)|bf16(h), tag=t+1.
// The tag IS the flag -> one store + one load per word, no fences/vmcnt drain.

#define T_SEQ 2048
#define BATCH 32
#define ISZ 512
#define HSZ 512
#define NG 32
#define CW 16
#define KP 520     // Bstage padded row (shorts)
#define XGP 36     // xg/hg padded row (floats), 16B-aligned

typedef short bf16x8 __attribute__((ext_vector_type(8)));
typedef float f32x4 __attribute__((ext_vector_type(4)));

__device__ __forceinline__ unsigned short f2bf(float f) {
  unsigned int u = __float_as_uint(f);
  unsigned int r = u + 0x7FFFu + ((u >> 16) & 1u);  // RTNE
  return (unsigned short)(r >> 16);
}

// Stage 32 rows x 512 f32 -> bf16 LDS [b][k]. Plain cached loads.
__device__ __forceinline__ void stage_plain(const float* base, long rowStride,
                                            unsigned short (*Bst)[KP], int tid) {
  if (tid < 256) {
    const int b = tid >> 3, part = tid & 7;
    const float* src = base + (long)b * rowStride;
#pragma unroll
    for (int i = 0; i < 16; ++i) {
      const int c16 = i * 8 + part;
      const float4 f = *(const float4*)(src + c16 * 4);
      ushort4 u;
      u.x = f2bf(f.x); u.y = f2bf(f.y); u.z = f2bf(f.z); u.w = f2bf(f.w);
      *(ushort4*)(&Bst[b][c16 * 4]) = u;
    }
  }
}

__device__ __forceinline__ f32x4 mfma_slab(const bf16x8* a,
                                           unsigned short (*Bst)[KP],
                                           int bt, int n16, int quad) {
  f32x4 acc = {0.f, 0.f, 0.f, 0.f};
#pragma unroll
  for (int kk = 0; kk < 16; ++kk) {
    const bf16x8 bf = *(const bf16x8*)(&Bst[bt * 16 + n16][kk * 32 + quad * 8]);
    acc = __builtin_amdgcn_mfma_f32_16x16x32_bf16(a[kk], bf, acc, 0, 0, 0);
  }
  return acc;
}

// Load one 48-row weight slab (rows rt*512+c0+n16 .. ) into A-fragments.
__device__ __forceinline__ void load_slab(const float* w, int rt, int c0,
                                          int n16, int quad, bf16x8* a) {
  const float* wr = w + (long)(rt * HSZ + c0 + n16) * HSZ;
#pragma unroll
  for (int kk = 0; kk < 16; ++kk) {
    const int k0 = kk * 32 + quad * 8;
    const float4 f0 = *(const float4*)(wr + k0);
    const float4 f1 = *(const float4*)(wr + k0 + 4);
    bf16x8 v;
    v[0] = (short)f2bf(f0.x); v[1] = (short)f2bf(f0.y);
    v[2] = (short)f2bf(f0.z); v[3] = (short)f2bf(f0.w);
    v[4] = (short)f2bf(f1.x); v[5] = (short)f2bf(f1.y);
    v[6] = (short)f2bf(f1.z); v[7] = (short)f2bf(f1.w);
    a[kk] = v;
  }
}

// ---------------- Phase 1: x_gates precompute ----------------
// grid (NG, 64): g = blockIdx.x, 32 t-values per wg. XF: 0=f32, 1=bf16.
template <int XF>
__global__ __launch_bounds__(384, 2) void ih_gemm(
    const float* __restrict__ in, const float* __restrict__ wih,
    void* __restrict__ xg_ws) {
  __shared__ unsigned short Bstage[BATCH][KP];
  const int tid = threadIdx.x;
  const int g = blockIdx.x, tc = blockIdx.y;
  const int lane = tid & 63, wid = tid >> 6;
  const int n16 = lane & 15, quad = lane >> 4;
  const int rt = wid % 3, bt = wid / 3;
  const int c0 = g * CW;

  bf16x8 a_ih[16];
  load_slab(wih, rt, c0, n16, quad, a_ih);

  for (int tt = 0; tt < 32; ++tt) {
    const int t = tc * 32 + tt;
    stage_plain(in + (long)t * ISZ, (long)T_SEQ * ISZ, Bstage, tid);
    __syncthreads();
    const f32x4 acc = mfma_slab(a_ih, Bstage, bt, n16, quad);
    const long base = ((long)t * NG + g) * 1536 + rt * 512 + bt * 16 + n16;
#pragma unroll
    for (int r = 0; r < 4; ++r) {
      const long idx = base + (quad * 4 + r) * 32;
      if (XF == 0) ((float*)xg_ws)[idx] = acc[r];
      else ((unsigned short*)xg_ws)[idx] = f2bf(acc[r]);
    }
    __syncthreads();
  }
}

// ---------------- Phase 2: recurrence ----------------
// MODE: 0 = xg fp32 in ws, 1 = xg bf16 in ws, 2 = fused (compute xg in-loop)
template <int MODE>
__global__ __launch_bounds__(384, 1) void gru_rec(
    const float* __restrict__ in, const float* __restrict__ h0,
    const float* __restrict__ wih, const float* __restrict__ whh,
    const float* __restrict__ bihp, const float* __restrict__ bhhp,
    float* __restrict__ out, unsigned int* __restrict__ ring,
    const void* __restrict__ xg_ws) {
  __shared__ unsigned short Bstage[BATCH][KP];
  __shared__ float xg[3][CW][XGP];
  __shared__ float hg[3][CW][XGP];
  __shared__ float own_h[CW][BATCH];
  __shared__ float bih_l[48], bhh_l[48];

  const int tid = threadIdx.x;
  const int g = blockIdx.x;
  const int c0 = g * CW;
  const int lane = tid & 63, wid = tid >> 6;
  const int n16 = lane & 15, quad = lane >> 4;
  const int rt = wid % 3, bt = wid / 3;

  if (tid < 48) bih_l[tid] = bihp[(tid >> 4) * HSZ + c0 + (tid & 15)];
  else if (tid >= 64 && tid < 112) {
    const int lr = tid - 64;
    bhh_l[lr] = bhhp[(lr >> 4) * HSZ + c0 + (lr & 15)];
  }

  bf16x8 a_hh[16];
  load_slab(whh, rt, c0, n16, quad, a_hh);
  bf16x8 a_ih[MODE == 2 ? 16 : 1];
  if (MODE == 2) load_slab(wih, rt, c0, n16, quad, a_ih);

  // ---- pre-loop: Bstage <- h0, own_h init, xg(0) ----
  stage_plain(h0, HSZ, Bstage, tid);
  if (tid < 256) {
    const int b = tid & 31, cb = (tid >> 5) << 1;
    own_h[cb][b] = h0[b * HSZ + c0 + cb];
    own_h[cb + 1][b] = h0[b * HSZ + c0 + cb + 1];
  }
  float4 xf;
  uint4 xu;
  if (MODE == 0) {
    xf = *(const float4*)((const float*)xg_ws + (long)g * 1536 + tid * 4);
  } else if (MODE == 1) {
    if (tid < 192)
      xu = *(const uint4*)((const unsigned short*)xg_ws + (long)g * 1536 + tid * 8);
  }
  __syncthreads();
  if (MODE == 2) {  // compute xg(0) into LDS (raw, bias added at gates)
    const f32x4 acc = mfma_slab(a_ih, Bstage, bt, n16, quad);
#pragma unroll
    for (int r = 0; r < 4; ++r) xg[rt][quad * 4 + r][bt * 16 + n16] = acc[r];
    __syncthreads();
  }

  for (int t = 0; t < T_SEQ; ++t) {
    // ---- Phase B: hg = W_hh @ h(t-1) ----
    {
      const f32x4 acc = mfma_slab(a_hh, Bstage, bt, n16, quad);
#pragma unroll
      for (int r = 0; r < 4; ++r) hg[rt][quad * 4 + r][bt * 16 + n16] = acc[r];
    }
    // scatter prefetched xg(t) into LDS (MODE 0/1)
    if (MODE == 0) {
      const int L = tid * 4;
      *(float4*)&xg[L >> 9][(L >> 5) & 15][L & 31] = xf;
    } else if (MODE == 1) {
      if (tid < 192) {
        const int L = tid * 8;
        float v[8];
        const unsigned int w[4] = {xu.x, xu.y, xu.z, xu.w};
#pragma unroll
        for (int j = 0; j < 4; ++j) {
          v[2 * j] = __uint_as_float((w[j] & 0xFFFFu) << 16);
          v[2 * j + 1] = __uint_as_float((w[j] >> 16) << 16);
        }
        float* dst = &xg[L >> 9][(L >> 5) & 15][L & 31];
        *(float4*)dst = make_float4(v[0], v[1], v[2], v[3]);
        *(float4*)(dst + 4) = make_float4(v[4], v[5], v[6], v[7]);
      }
    }
    __syncthreads();

    // ---- gates + stores ----
    if (tid < 256) {
      const int b = tid & 31, cb = (tid >> 5) << 1;
      float h2[2];
#pragma unroll
      for (int j = 0; j < 2; ++j) {
        const int col = cb + j;
        const float xr = xg[0][col][b] + bih_l[col];
        const float xz = xg[1][col][b] + bih_l[16 + col];
        const float xn = xg[2][col][b] + bih_l[32 + col];
        const float hr = hg[0][col][b] + bhh_l[col];
        const float hz = hg[1][col][b] + bhh_l[16 + col];
        const float hn = hg[2][col][b] + bhh_l[32 + col];
        const float r = 1.f / (1.f + __expf(-(xr + hr)));
        const float z = 1.f / (1.f + __expf(-(xz + hz)));
        const float aa = xn + r * hn;
        const float e = __expf(-2.f * fabsf(aa));
        float th = (1.f - e) / (1.f + e);
        th = copysignf(th, aa);
        const float hp = own_h[col][b];
        const float hnew = (1.f - z) * th + z * hp;
        own_h[col][b] = hnew;
        h2[j] = hnew;
      }
      // tagged ring store first (critical path), then cached out store
      const unsigned int tg = (unsigned int)(t + 1);
      const unsigned int w0 = (unsigned int)f2bf(h2[0]) | (tg << 16);
      const unsigned int w1 = (unsigned int)f2bf(h2[1]) | (tg << 16);
      const unsigned long long wv = ((unsigned long long)w1 << 32) | w0;
      __hip_atomic_store(
          (unsigned long long*)(ring + ((t & 3) * BATCH + b) * HSZ + c0 + cb),
          wv, __ATOMIC_RELAXED, __HIP_MEMORY_SCOPE_AGENT);
      *(float2*)(out + (long)b * T_SEQ * HSZ + (long)t * HSZ + c0 + cb) =
          make_float2(h2[0], h2[1]);
    }

    // prefetch xg(t+1) (MODE 0/1) — independent, hides under poll
    if (MODE == 0) {
      const int tn = (t + 1 < T_SEQ) ? t + 1 : t;
      xf = *(const float4*)((const float*)xg_ws + ((long)tn * NG + g) * 1536 +
                            tid * 4);
    } else if (MODE == 1) {
      if (tid < 192) {
        const int tn = (t + 1 < T_SEQ) ? t + 1 : t;
        xu = *(const uint4*)((const unsigned short*)xg_ws +
                             ((long)tn * NG + g) * 1536 + tid * 8);
      }
    }

    if (MODE == 2 && t + 1 < T_SEQ) {
      __syncthreads();  // Bstage reads (Phase B) done; reuse for input staging
      stage_plain(in + (long)(t + 1) * ISZ, (long)T_SEQ * ISZ, Bstage, tid);
      __syncthreads();
      const f32x4 acc = mfma_slab(a_ih, Bstage, bt, n16, quad);
      __syncthreads();  // orders gates' xg(t) reads before xg(t+1) writes
#pragma unroll
      for (int r = 0; r < 4; ++r) xg[rt][quad * 4 + r][bt * 16 + n16] = acc[r];
    }

    // ---- poll h(t) from ring into Bstage (tagged) ----
    if (t + 1 < T_SEQ && tid < 256) {
      const int b = tid >> 3, part = tid & 7;
      const unsigned long long* src = (const unsigned long long*)(
          ring + ((t & 3) * BATCH + b) * HSZ + part * 64);
      const unsigned long long tg = (unsigned long long)(t + 1);
      const unsigned long long patt = (tg << 48) | (tg << 16);
      const unsigned long long msk = 0xFFFF0000FFFF0000ull;
      unsigned long long tmp[32];
#pragma unroll
      for (int i = 0; i < 32; ++i)
        tmp[i] = __hip_atomic_load(&src[i], __ATOMIC_RELAXED,
                                   __HIP_MEMORY_SCOPE_AGENT);
      unsigned int vm = 0;
      while (vm != 0xFFFFFFFFu) {
#pragma unroll
        for (int i = 0; i < 32; ++i) {
          if (vm & (1u << i)) continue;
          const unsigned long long v = tmp[i];
          if ((v & msk) == patt) {
            const unsigned int p =
                (unsigned int)(v & 0xFFFFu) | ((unsigned int)(v >> 32) << 16);
            *(unsigned int*)&Bstage[b][part * 64 + i * 2] = p;
            vm |= (1u << i);
          } else {
            tmp[i] = __hip_atomic_load(&src[i], __ATOMIC_RELAXED,
                                       __HIP_MEMORY_SCOPE_AGENT);
          }
        }
      }
    }
    __syncthreads();
  }
}

extern "C" void kernel_launch(void* const* d_in, const int* in_sizes, int n_in,
                              void* d_out, int out_size, void* d_ws,
                              size_t ws_size, hipStream_t stream) {
  const float* in = (const float*)d_in[0];
  const float* h0 = (const float*)d_in[1];
  const float* wih = (const float*)d_in[2];
  const float* whh = (const float*)d_in[3];
  const float* bih = (const float*)d_in[4];
  const float* bhh = (const float*)d_in[5];
  float* out = (float*)d_out;

  unsigned int* ring = (unsigned int*)d_ws;  // 4 slots * 32 * 512 u32 = 256 KB
  void* xg_ws = (void*)((char*)d_ws + 262144);
  const size_t xg32 = (size_t)T_SEQ * BATCH * 1536 * 4;  // 402.7 MB
  const size_t xg16 = xg32 / 2;

  if (ws_size >= 262144 + xg32) {
    ih_gemm<0><<<dim3(NG, 64), dim3(384), 0, stream>>>(in, wih, xg_ws);
    gru_rec<0><<<dim3(NG), dim3(384), 0, stream>>>(in, h0, wih, whh, bih, bhh,
                                                   out, ring, xg_ws);
  } else if (ws_size >= 262144 + xg16) {
    ih_gemm<1><<<dim3(NG, 64), dim3(384), 0, stream>>>(in, wih, xg_ws);
    gru_rec<1><<<dim3(NG), dim3(384), 0, stream>>>(in, h0, wih, whh, bih, bhh,
                                                   out, ring, xg_ws);
  } else {
    gru_rec<2><<<dim3(NG), dim3(384), 0, stream>>>(in, h0, wih, whh, bih, bhh,
                                                   out, ring, xg_ws);
  }
}